// Round 9
// baseline (21230.510 us; speedup 1.0000x reference)
//
#include <hip/hip_runtime.h>
#include <stdint.h>

#define TS 4096
#define NEG_VAL -1000000000.0f

typedef _Float16 h2    __attribute__((ext_vector_type(2)));
typedef _Float16 f16x8 __attribute__((ext_vector_type(8)));
typedef unsigned long long u64t;

// ---------------- workspace layout (bytes) ----------------
#define GI0H_OFF  ((size_t)0)                    // 4096*768*4 = 12582912 (f16-packed gi0)
#define H1_OFF    ((size_t)12582912)             // 4096*512*4 = 8388608
#define MB0L0_OFF ((size_t)20971520)             // 8 cons * 32 slots * 256 w * 8B = 524288
#define MB0L1_OFF ((size_t)21495808)             // 16*32*256*8 = 1048576
#define MB1L1_OFF ((size_t)22544384)             // 16*32*256*8 = 1048576
#define PROGS_OFF ((size_t)23592960)             // 24 * 64B
#define PROGH_OFF ((size_t)23594496)             // 64 u32
#define TICK_OFF  ((size_t)23594752)
#define WS_NEED   ((size_t)23594816)

// ---------------- helpers ----------------
static __device__ __forceinline__ u64t ld_a64(const u64t* p){
  return __hip_atomic_load(p, __ATOMIC_RELAXED, __HIP_MEMORY_SCOPE_AGENT);
}
static __device__ __forceinline__ void st_a64(u64t* p, u64t v){
  __hip_atomic_store(p, v, __ATOMIC_RELAXED, __HIP_MEMORY_SCOPE_AGENT);
}
static __device__ __forceinline__ unsigned ld_u32(const unsigned* p){
  return __hip_atomic_load(p, __ATOMIC_RELAXED, __HIP_MEMORY_SCOPE_AGENT);
}
static __device__ __forceinline__ void st_u32(unsigned* p, unsigned v){
  __hip_atomic_store(p, v, __ATOMIC_RELAXED, __HIP_MEMORY_SCOPE_AGENT);
}
static __device__ __forceinline__ float sigmoidf_(float x){
  return 1.0f / (1.0f + __expf(-x));
}
static __device__ __forceinline__ float tanhf_(float x){
  float ax = fabsf(x);
  float e  = __expf(-2.0f*ax);
  float t  = (1.0f - e) / (1.0f + e);
  return copysignf(t, x);
}
static __device__ __forceinline__ uint32_t pack2h(float a, float b){
  _Float16 ha = (_Float16)a, hb = (_Float16)b;
  unsigned short ua = __builtin_bit_cast(unsigned short, ha);
  unsigned short ub = __builtin_bit_cast(unsigned short, hb);
  return (uint32_t)ua | ((uint32_t)ub << 16);
}
static __device__ __forceinline__ h2 u2h2(uint32_t u){ return __builtin_bit_cast(h2, u); }
static __device__ __forceinline__ unsigned tg(u64t v){ return (unsigned)(v>>32); }

template<int CTRL>
static __device__ __forceinline__ float dppx(float x){
  return __int_as_float(__builtin_amdgcn_update_dpp(0, __float_as_int(x), CTRL, 0xF, 0xF, true));
}
static __device__ __forceinline__ float qsum8(float x){
  x += dppx<0xB1>(x); x += dppx<0x4E>(x); x += __shfl_xor(x, 4, 64);
  return x;
}
static __device__ __forceinline__ float qsum16(float x){
  x += dppx<0xB1>(x); x += dppx<0x4E>(x); x += __shfl_xor(x, 4, 64); x += __shfl_xor(x, 8, 64);
  return x;
}
static __device__ __forceinline__ int wave_min(int v){
  #pragma unroll
  for (int off=32; off; off>>=1){ int o = __shfl_xor(v, off, 64); v = o<v?o:v; }
  return v;
}

#if __has_builtin(__builtin_amdgcn_fdot2)
static __device__ __forceinline__ float FDOT2(h2 a, h2 b, float c){
  return __builtin_amdgcn_fdot2(a, b, c, false);
}
#else
static __device__ __forceinline__ float FDOT2(h2 a, h2 b, float c){
  return c + (float)a[0]*(float)b[0] + (float)a[1]*(float)b[1];
}
#endif

static __device__ __forceinline__ float dot8(f16x8 wv, const uint32_t* hw, float acc){
  acc = FDOT2(h2{wv[0],wv[1]}, u2h2(hw[0]), acc);
  acc = FDOT2(h2{wv[2],wv[3]}, u2h2(hw[1]), acc);
  acc = FDOT2(h2{wv[4],wv[5]}, u2h2(hw[2]), acc);
  acc = FDOT2(h2{wv[6],wv[7]}, u2h2(hw[3]), acc);
  return acc;
}

// named-register weight machinery (forces SSA -> VGPR residency)
#define DECL8(P) f16x8 P##0,P##1,P##2,P##3,P##4,P##5,P##6,P##7;
#define DECL4(P) f16x8 P##0,P##1,P##2,P##3;
#define LDW8(DST, PTR) { float4 _a=((const float4*)(PTR))[0]; float4 _b=((const float4*)(PTR))[1]; \
  DST = f16x8{(_Float16)_a.x,(_Float16)_a.y,(_Float16)_a.z,(_Float16)_a.w, \
              (_Float16)_b.x,(_Float16)_b.y,(_Float16)_b.z,(_Float16)_b.w}; }
#define LOADROW8(P, BASE) LDW8(P##0,(BASE)) LDW8(P##1,(BASE)+8) LDW8(P##2,(BASE)+16) LDW8(P##3,(BASE)+24) \
                          LDW8(P##4,(BASE)+32) LDW8(P##5,(BASE)+40) LDW8(P##6,(BASE)+48) LDW8(P##7,(BASE)+56)
#define LOADROW4(P, BASE) LDW8(P##0,(BASE)) LDW8(P##1,(BASE)+8) LDW8(P##2,(BASE)+16) LDW8(P##3,(BASE)+24)
#define DOT8x8(ACC,P,HW) ACC=dot8(P##0,(HW)+0,ACC);ACC=dot8(P##1,(HW)+4,ACC);ACC=dot8(P##2,(HW)+8,ACC);ACC=dot8(P##3,(HW)+12,ACC); \
                         ACC=dot8(P##4,(HW)+16,ACC);ACC=dot8(P##5,(HW)+20,ACC);ACC=dot8(P##6,(HW)+24,ACC);ACC=dot8(P##7,(HW)+28,ACC);
#define DOT8x4(ACC,P,HW) ACC=dot8(P##0,(HW)+0,ACC);ACC=dot8(P##1,(HW)+4,ACC);ACC=dot8(P##2,(HW)+8,ACC);ACC=dot8(P##3,(HW)+12,ACC);

// ================= fused kernel: 256 WGs x 512 thr =================
// blockIdx%8==0 && blockIdx<192 -> scan role = blockIdx/8 (same-XCD co-location):
//   role 0..7  : layer0 (Whh0; 64 out; 8 lanes/out; 24 named f16x8 weights)
//   role 8..23 : layer1 (Whh1+Wih1; 32 out; 16 lanes/out; 24 named f16x8)
// all other WGs: FC GEMM workers.
// mailbox word = tag(step+2)<<32 | 2xf16 ; seed h(-1) at slot 31 tag 1. Ring 32.
__global__ __launch_bounds__(512,1) void actor_fused(
    const float* __restrict__ hprev,
    const int*   __restrict__ mask,
    const float* __restrict__ Whh0,
    const float* __restrict__ bhh0,
    const float* __restrict__ Wih1,
    const float* __restrict__ Whh1,
    const float* __restrict__ bih1,
    const float* __restrict__ bhh1,
    const float* __restrict__ Wfc,
    const float* __restrict__ bfc,
    const uint32_t* __restrict__ gi0h,
    float* __restrict__ H1,
    u64t* mb0l0, u64t* mb0l1, u64t* mb1l1,
    unsigned* progS, unsigned* progH, unsigned* ticket,
    float* __restrict__ out, float* __restrict__ hnext)
{
  const int bx   = blockIdx.x;
  const int tid  = threadIdx.x;
  const int wv   = tid >> 6;
  const int lane = tid & 63;
  const bool isScan = ((bx & 7) == 0) && (bx < 192);
  const int role = bx >> 3;

  __shared__ __align__(16) uint32_t smem[6784];
  long bd = 1L<<22;
  bool fail = false;

  if (isScan && role < 8){
    // ===================== layer 0 =====================
    const int o = role*64 + (tid>>3);
    const int j = tid&7;
    DECL8(Ar) DECL8(Az) DECL8(An)
    LOADROW8(Ar, Whh0 + (size_t)o*512         + 64*j)
    LOADROW8(Az, Whh0 + (size_t)(512+o)*512   + 64*j)
    LOADROW8(An, Whh0 + (size_t)(1024+o)*512  + 64*j)
    const float br=bhh0[o], bz=bhh0[512+o], bn=bhh0[1024+o];
    float hreg = hprev[o];
    u64t* mbme = mb0l0 + (size_t)role*32*256;
    volatile int* flg = (volatile int*)(smem+600);
    volatile int* fcp = (volatile int*)(smem+604);
    if ((tid&1)==0)
      st_a64(mbme + (size_t)31*256 + (tid>>1), ((u64t)1<<32) | pack2h(hprev[tid], hprev[tid+1]));
    if (tid==0){ flg[0]=-1; flg[1]=-1; fcp[0]=-1; }
    __syncthreads();
    u64t p0=0,p1=0,p2=0,p3=0;
    if (wv==0){
      const u64t* b = mbme + (size_t)31*256 + 4*lane;
      p0=ld_a64(b); p1=ld_a64(b+1); p2=ld_a64(b+2); p3=ld_a64(b+3);
    }

    for (int t=0; t<TS; ++t){
      if ((t&3)==0 && wv==2 && lane==0) st_u32(progS + role*16, (unsigned)t);
      if ((t&15)==8 && t>=32){
        if (wv==2){
          const int need = t-10;
          int v = (lane<24)? (int)ld_u32(progS + lane*16) : 0x7fffffff;
          int mn = wave_min(v);
          while (mn < need){
            if (--bd<0){ fail=true; break; }
            __builtin_amdgcn_s_sleep(8);
            v = (lane<24)? (int)ld_u32(progS + lane*16) : 0x7fffffff;
            mn = wave_min(v);
          }
          if (lane==0) fcp[0] = t;
        } else {
          int c=0;
          while (fcp[0] < t){ if(++c>(1<<20)){fail=true;break;} __builtin_amdgcn_s_sleep(4); }
        }
        if (fail) break;
      }
      // gi0 (f16-packed, includes bih0) issued early
      const uint32_t* gp = gi0h + (size_t)t*768 + (o>>1);
      const uint32_t ga=gp[0], gb=gp[256], gc=gp[512];

      if (wv==0){
        const unsigned want = (unsigned)(t+1);
        const u64t* b = mbme + (size_t)((t-1)&31)*256 + 4*lane;
        int it=0;
        for(;;){
          bool ok = (tg(p0)==want)&&(tg(p1)==want)&&(tg(p2)==want)&&(tg(p3)==want);
          if (__all(ok)) break;
          if (--bd<0){ fail=true; break; }
          if (++it>16) __builtin_amdgcn_s_sleep(2);
          if (tg(p0)!=want) p0=ld_a64(b);
          if (tg(p1)!=want) p1=ld_a64(b+1);
          if (tg(p2)!=want) p2=ld_a64(b+2);
          if (tg(p3)!=want) p3=ld_a64(b+3);
        }
        uint32_t* dst = smem + (t&1)*288 + 4*lane + 4*(lane>>3);
        dst[0]=(uint32_t)p0; dst[1]=(uint32_t)p1; dst[2]=(uint32_t)p2; dst[3]=(uint32_t)p3;
        asm volatile("s_waitcnt lgkmcnt(0)" ::: "memory");
        if (fail){ flg[0]=0x7fffffff; flg[1]=0x7fffffff; break; }
        if (lane==0) flg[t&1] = t;
      }
      { int c=0, fv;
        while ((fv=flg[t&1]) != t){
          if (fv>=0x40000000){ fail=true; break; }
          if (++c>(1<<20)){ fail=true; break; }
          __builtin_amdgcn_s_sleep(1);
        }
        if (fail) break;
      }
      asm volatile("" ::: "memory");
      uint32_t hw[32];
      { const uint32_t* src = smem + (t&1)*288 + 36*j;
        #pragma unroll
        for (int k2=0;k2<8;++k2){
          uint4 u = *(const uint4*)(src + 4*k2);
          hw[4*k2]=u.x; hw[4*k2+1]=u.y; hw[4*k2+2]=u.z; hw[4*k2+3]=u.w;
        } }
      float a0=0.f,a1=0.f,a2=0.f;
      DOT8x8(a0,Ar,hw) DOT8x8(a1,Az,hw) DOT8x8(a2,An,hw)
      a0=qsum8(a0); a1=qsum8(a1); a2=qsum8(a2);

      h2 g0=u2h2(ga), g1=u2h2(gb), g2=u2h2(gc);
      const int half = o&1;
      const float gr = half? (float)g0[1] : (float)g0[0];
      const float gz = half? (float)g1[1] : (float)g1[0];
      const float gn = half? (float)g2[1] : (float)g2[0];

      const float r = sigmoidf_(gr + a0 + br);
      const float z = sigmoidf_(gz + a1 + bz);
      const float n = tanhf_(gn + r*(a2 + bn));
      const float h = (1.f - z)*n + z*hreg;
      hreg = h;

      const float hx = __shfl_xor(h, 8, 64);
      const uint32_t wval = half? pack2h(hx,h) : pack2h(h,hx);
      const u64t word = ((u64t)(unsigned)(t+2)<<32) | wval;
      const int wi = role*32 + (tid>>4);
      const int d = (tid&7) | (((tid>>3)&1)<<3);
      const int slot = t&31;
      if (d<8){
        st_a64(mb0l0 + ((size_t)d*32 + slot)*256 + wi, word);
        st_a64(mb0l1 + ((size_t)(8+d)*32 + slot)*256 + wi, word);
      } else {
        st_a64(mb0l1 + ((size_t)(d-8)*32 + slot)*256 + wi, word);
      }
      if (t==TS-1 && j==0) hnext[o] = h;
      if (wv==0){
        const u64t* b = mbme + (size_t)(t&31)*256 + 4*lane;
        p0=ld_a64(b); p1=ld_a64(b+1); p2=ld_a64(b+2); p3=ld_a64(b+3);
      }
    }
  } else if (isScan){
    // ===================== layer 1 (ih folded) =====================
    const int q = role-8;
    const int ol = q*32 + (tid>>4);
    const int j = lane&15;
    DECL4(Hr) DECL4(Hz) DECL4(Hn) DECL4(Ir) DECL4(Iz) DECL4(In)
    LOADROW4(Hr, Whh1 + (size_t)ol*512         + 32*j)
    LOADROW4(Hz, Whh1 + (size_t)(512+ol)*512   + 32*j)
    LOADROW4(Hn, Whh1 + (size_t)(1024+ol)*512  + 32*j)
    LOADROW4(Ir, Wih1 + (size_t)ol*512         + 32*j)
    LOADROW4(Iz, Wih1 + (size_t)(512+ol)*512   + 32*j)
    LOADROW4(In, Wih1 + (size_t)(1024+ol)*512  + 32*j)
    const float brc = bih1[ol] + bhh1[ol];
    const float bzc = bih1[512+ol] + bhh1[512+ol];
    const float bin = bih1[1024+ol];
    const float bhn = bhh1[1024+ol];
    float hreg = hprev[512+ol];
    u64t* mb1me = mb1l1 + (size_t)q*32*256;
    u64t* mb0me = mb0l1 + (size_t)q*32*256;
    volatile int* flgA = (volatile int*)(smem+1160);  // h1 flags [2]
    volatile int* flgB = (volatile int*)(smem+1162);  // h0 flags [2]
    volatile int* fcp  = (volatile int*)(smem+1166);
    if ((tid&1)==0)
      st_a64(mb1me + (size_t)31*256 + (tid>>1), ((u64t)1<<32) | pack2h(hprev[512+tid], hprev[512+tid+1]));
    if (tid==0){ flgA[0]=-1; flgA[1]=-1; flgB[0]=-1; flgB[1]=-1; fcp[0]=-1; }
    __syncthreads();
    u64t pa0=0,pa1=0,pa2=0,pa3=0, pb0=0,pb1=0,pb2=0,pb3=0;
    if (wv==0){
      const u64t* b = mb1me + (size_t)31*256 + 4*lane;
      pa0=ld_a64(b); pa1=ld_a64(b+1); pa2=ld_a64(b+2); pa3=ld_a64(b+3);
    } else if (wv==1){
      const u64t* b = mb0me + 4*lane;
      pb0=ld_a64(b); pb1=ld_a64(b+1); pb2=ld_a64(b+2); pb3=ld_a64(b+3);
    }

    for (int s=0; s<TS; ++s){
      if ((s&3)==0 && wv==2 && lane==32) st_u32(progS + role*16, (unsigned)s);
      if ((s&15)==8 && s>=32){
        if (wv==2){
          const int need = s-10;
          int v = (lane<16)? (int)ld_u32(progS + (8+lane)*16) : 0x7fffffff;
          int mn = wave_min(v);
          while (mn < need){
            if (--bd<0){ fail=true; break; }
            __builtin_amdgcn_s_sleep(8);
            v = (lane<16)? (int)ld_u32(progS + (8+lane)*16) : 0x7fffffff;
            mn = wave_min(v);
          }
          if (lane==0) fcp[0] = s;
        } else {
          int c=0;
          while (fcp[0] < s){ if(++c>(1<<20)){fail=true;break;} __builtin_amdgcn_s_sleep(4); }
        }
        if (fail) break;
      }
      if (wv==0){          // h1(s-1) poll -> LDS buf A
        const unsigned want = (unsigned)(s+1);
        const u64t* b = mb1me + (size_t)((s-1)&31)*256 + 4*lane;
        int it=0;
        for(;;){
          bool ok = (tg(pa0)==want)&&(tg(pa1)==want)&&(tg(pa2)==want)&&(tg(pa3)==want);
          if (__all(ok)) break;
          if (--bd<0){ fail=true; break; }
          if (++it>16) __builtin_amdgcn_s_sleep(2);
          if (tg(pa0)!=want) pa0=ld_a64(b);
          if (tg(pa1)!=want) pa1=ld_a64(b+1);
          if (tg(pa2)!=want) pa2=ld_a64(b+2);
          if (tg(pa3)!=want) pa3=ld_a64(b+3);
        }
        uint32_t* dst = smem + (s&1)*288 + 4*lane + 4*(lane>>3);
        dst[0]=(uint32_t)pa0; dst[1]=(uint32_t)pa1; dst[2]=(uint32_t)pa2; dst[3]=(uint32_t)pa3;
        asm volatile("s_waitcnt lgkmcnt(0)" ::: "memory");
        if (fail){ flgA[0]=0x7fffffff; flgA[1]=0x7fffffff; break; }
        if (lane==0) flgA[s&1] = s;
      } else if (wv==1){   // h0(s) poll -> LDS buf B
        const unsigned want = (unsigned)(s+2);
        const u64t* b = mb0me + (size_t)(s&31)*256 + 4*lane;
        int it=0;
        for(;;){
          bool ok = (tg(pb0)==want)&&(tg(pb1)==want)&&(tg(pb2)==want)&&(tg(pb3)==want);
          if (__all(ok)) break;
          if (--bd<0){ fail=true; break; }
          if (++it>16) __builtin_amdgcn_s_sleep(2);
          if (tg(pb0)!=want) pb0=ld_a64(b);
          if (tg(pb1)!=want) pb1=ld_a64(b+1);
          if (tg(pb2)!=want) pb2=ld_a64(b+2);
          if (tg(pb3)!=want) pb3=ld_a64(b+3);
        }
        uint32_t* dst = smem + 576 + (s&1)*288 + 4*lane + 4*(lane>>3);
        dst[0]=(uint32_t)pb0; dst[1]=(uint32_t)pb1; dst[2]=(uint32_t)pb2; dst[3]=(uint32_t)pb3;
        asm volatile("s_waitcnt lgkmcnt(0)" ::: "memory");
        if (fail){ flgB[0]=0x7fffffff; flgB[1]=0x7fffffff; break; }
        if (lane==0) flgB[s&1] = s;
      }
      { int c=0, fv;
        while ((fv=flgA[s&1]) != s){
          if (fv>=0x40000000){ fail=true; break; }
          if (++c>(1<<20)){ fail=true; break; }
          __builtin_amdgcn_s_sleep(1);
        }
        while (!fail && (fv=flgB[s&1]) != s){
          if (fv>=0x40000000){ fail=true; break; }
          if (++c>(1<<20)){ fail=true; break; }
          __builtin_amdgcn_s_sleep(1);
        }
        if (fail) break;
      }
      asm volatile("" ::: "memory");
      uint32_t h1w[16], h0w[16];
      { const int off = 16*j + 4*(j>>1);
        const uint32_t* sa = smem + (s&1)*288 + off;
        const uint32_t* sb = smem + 576 + (s&1)*288 + off;
        #pragma unroll
        for (int k2=0;k2<4;++k2){
          uint4 u = *(const uint4*)(sa + 4*k2);
          h1w[4*k2]=u.x; h1w[4*k2+1]=u.y; h1w[4*k2+2]=u.z; h1w[4*k2+3]=u.w;
          uint4 v = *(const uint4*)(sb + 4*k2);
          h0w[4*k2]=v.x; h0w[4*k2+1]=v.y; h0w[4*k2+2]=v.z; h0w[4*k2+3]=v.w;
        } }
      float a0=0.f,a1=0.f,a2=0.f,b0=0.f,b1=0.f,b2=0.f;
      DOT8x4(a0,Hr,h1w) DOT8x4(a1,Hz,h1w) DOT8x4(a2,Hn,h1w)
      DOT8x4(b0,Ir,h0w) DOT8x4(b1,Iz,h0w) DOT8x4(b2,In,h0w)
      const float sr  = qsum16(a0+b0);
      const float sz  = qsum16(a1+b1);
      const float shn = qsum16(a2);
      const float sin_= qsum16(b2);

      const float r = sigmoidf_(sr + brc);
      const float z = sigmoidf_(sz + bzc);
      const float n = tanhf_((sin_ + bin) + r*(shn + bhn));
      const float h = (1.f - z)*n + z*hreg;
      hreg = h;

      if ((tid&15)==0) H1[(size_t)s*512 + ol] = h;
      const float hx = __shfl_xor(h, 16, 64);
      const uint32_t wval = (ol&1)? pack2h(hx,h) : pack2h(h,hx);
      const u64t word = ((u64t)(unsigned)(s+2)<<32) | wval;
      const int wi = q*16 + (tid>>5);
      const int d = (tid&15) | (((tid>>4)&1)<<4);
      if (d<16)
        st_a64(mb1l1 + ((size_t)d*32 + (s&31))*256 + wi, word);
      if ((s&15)==15 && wv==3 && lane==32)
        __hip_atomic_store(progH + q, (unsigned)(s-4),
                           __ATOMIC_RELEASE, __HIP_MEMORY_SCOPE_AGENT);
      if (s==TS-1 && (tid&15)==0) hnext[512+ol] = h;
      if (wv==0){
        const u64t* b = mb1me + (size_t)(s&31)*256 + 4*lane;
        pa0=ld_a64(b); pa1=ld_a64(b+1); pa2=ld_a64(b+2); pa3=ld_a64(b+3);
      } else if (wv==1){
        const u64t* b = mb0me + (size_t)((s+1)&31)*256 + 4*lane;
        pb0=ld_a64(b); pb1=ld_a64(b+1); pb2=ld_a64(b+2); pb3=ld_a64(b+3);
      }
    }
    __syncthreads();
    if (tid==0)
      __hip_atomic_store(progH + q, (unsigned)TS,
                         __ATOMIC_RELEASE, __HIP_MEMORY_SCOPE_AGENT);
  } else {
    // ===================== FC GEMM workers =====================
    float* As = (float*)smem;          // [32][132]
    float* Bs = As + 32*132;           // [32][68]
    int*   comm = (int*)&smem[6780];
    const int tm = tid>>4, tn = tid&15;
    const int m0 = tid>>2, kk0a = (tid&3)*8;
    const int n0 = tid>>3, kk0b = (tid&7)*4;
    long fcbd = 1L<<24;
    for(;;){
      if (tid==0) comm[0] = (int)atomicAdd(ticket, 1u);
      __syncthreads();
      const int tau = comm[0];
      __syncthreads();
      if (tau >= 2048) break;
      const int bm = tau>>6, bn = tau&63;
      if (tid==0){
        const unsigned need = (unsigned)(bm*128 + 128);
        for(;;){
          unsigned mn = 0xffffffffu;
          for (int k2=0;k2<16;++k2){ unsigned v = ld_u32(progH+k2); mn = v<mn?v:mn; }
          if (mn >= need) break;
          __builtin_amdgcn_s_sleep(32);
          if (--fcbd < 0) break;
        }
      }
      __syncthreads();
      __builtin_amdgcn_fence(__ATOMIC_ACQUIRE, "agent");

      const float* A = H1  + (size_t)bm*128*512;
      const float* B = Wfc + (size_t)bn*64*512;
      float acc[4][4] = {};
      for (int k0=0; k0<512; k0+=32){
        #pragma unroll
        for (int jj=0;jj<8;++jj) As[(kk0a+jj)*132 + m0] = A[(size_t)m0*512 + k0+kk0a+jj];
        #pragma unroll
        for (int jj=0;jj<4;++jj) Bs[(kk0b+jj)*68  + n0] = B[(size_t)n0*512 + k0+kk0b+jj];
        __syncthreads();
        #pragma unroll
        for (int kk=0;kk<32;++kk){
          const float4 av = *(const float4*)&As[kk*132 + tm*4];
          const float4 bv = *(const float4*)&Bs[kk*68  + tn*4];
          acc[0][0]=fmaf(av.x,bv.x,acc[0][0]); acc[0][1]=fmaf(av.x,bv.y,acc[0][1]);
          acc[0][2]=fmaf(av.x,bv.z,acc[0][2]); acc[0][3]=fmaf(av.x,bv.w,acc[0][3]);
          acc[1][0]=fmaf(av.y,bv.x,acc[1][0]); acc[1][1]=fmaf(av.y,bv.y,acc[1][1]);
          acc[1][2]=fmaf(av.y,bv.z,acc[1][2]); acc[1][3]=fmaf(av.y,bv.w,acc[1][3]);
          acc[2][0]=fmaf(av.z,bv.x,acc[2][0]); acc[2][1]=fmaf(av.z,bv.y,acc[2][1]);
          acc[2][2]=fmaf(av.z,bv.z,acc[2][2]); acc[2][3]=fmaf(av.z,bv.w,acc[2][3]);
          acc[3][0]=fmaf(av.w,bv.x,acc[3][0]); acc[3][1]=fmaf(av.w,bv.y,acc[3][1]);
          acc[3][2]=fmaf(av.w,bv.z,acc[3][2]); acc[3][3]=fmaf(av.w,bv.w,acc[3][3]);
        }
        __syncthreads();
      }
      const int cc0 = bn*64 + tn*4;
      const int mk0 = mask[cc0], mk1 = mask[cc0+1], mk2 = mask[cc0+2], mk3 = mask[cc0+3];
      const float c0 = bfc[cc0], c1 = bfc[cc0+1], c2 = bfc[cc0+2], c3 = bfc[cc0+3];
      #pragma unroll
      for (int i=0;i<4;++i){
        const int mm = bm*128 + tm*4 + i;
        float4 vv;
        vv.x = fmaxf(acc[i][0]+c0, 0.f); if (mk0==0) vv.x = NEG_VAL;
        vv.y = fmaxf(acc[i][1]+c1, 0.f); if (mk1==0) vv.y = NEG_VAL;
        vv.z = fmaxf(acc[i][2]+c2, 0.f); if (mk2==0) vv.z = NEG_VAL;
        vv.w = fmaxf(acc[i][3]+c3, 0.f); if (mk3==0) vv.w = NEG_VAL;
        *(float4*)&out[(size_t)mm*4096 + cc0] = vv;
      }
    }
  }
}

// ---------------- gi0h = f16pack(state[:,1:] @ Wih0^T + bih0) ----------------
__global__ __launch_bounds__(256) void gemm_gi0(
    const float* __restrict__ A, int lda,
    const float* __restrict__ B, int ldb,
    uint32_t* __restrict__ C,
    const float* __restrict__ bias, int K)
{
  __shared__ __align__(16) float As[32][68];
  __shared__ __align__(16) float Bs[32][68];
  const int bm = blockIdx.y*64, bn = blockIdx.x*64;
  const int tid = threadIdx.x;
  const int tm = tid>>4, tn = tid&15;
  float acc[4][4] = {};
  const int m0 = tid>>2, kk0 = (tid&3)*8;
  for (int k0=0; k0<K; k0+=32){
    #pragma unroll
    for (int j=0;j<8;++j) As[kk0+j][m0] = A[(size_t)(bm+m0)*lda + k0+kk0+j];
    #pragma unroll
    for (int j=0;j<8;++j) Bs[kk0+j][m0] = B[(size_t)(bn+m0)*ldb + k0+kk0+j];
    __syncthreads();
    #pragma unroll
    for (int kk=0;kk<32;++kk){
      const float4 av = *(const float4*)&As[kk][tm*4];
      const float4 bv = *(const float4*)&Bs[kk][tn*4];
      acc[0][0]=fmaf(av.x,bv.x,acc[0][0]); acc[0][1]=fmaf(av.x,bv.y,acc[0][1]);
      acc[0][2]=fmaf(av.x,bv.z,acc[0][2]); acc[0][3]=fmaf(av.x,bv.w,acc[0][3]);
      acc[1][0]=fmaf(av.y,bv.x,acc[1][0]); acc[1][1]=fmaf(av.y,bv.y,acc[1][1]);
      acc[1][2]=fmaf(av.y,bv.z,acc[1][2]); acc[1][3]=fmaf(av.y,bv.w,acc[1][3]);
      acc[2][0]=fmaf(av.z,bv.x,acc[2][0]); acc[2][1]=fmaf(av.z,bv.y,acc[2][1]);
      acc[2][2]=fmaf(av.z,bv.z,acc[2][2]); acc[2][3]=fmaf(av.z,bv.w,acc[2][3]);
      acc[3][0]=fmaf(av.w,bv.x,acc[3][0]); acc[3][1]=fmaf(av.w,bv.y,acc[3][1]);
      acc[3][2]=fmaf(av.w,bv.z,acc[3][2]); acc[3][3]=fmaf(av.w,bv.w,acc[3][3]);
    }
    __syncthreads();
  }
  const int cc0 = bn + tn*4;
  const int g = cc0 >> 9, c0 = cc0 & 511;
  const float b0=bias[cc0], b1=bias[cc0+1], b2=bias[cc0+2], b3=bias[cc0+3];
  #pragma unroll
  for (int i=0;i<4;++i){
    const int mm = bm + tm*4 + i;
    uint2 pw;
    pw.x = ((uint32_t)__builtin_bit_cast(unsigned short,(_Float16)(acc[i][0]+b0))) |
           (((uint32_t)__builtin_bit_cast(unsigned short,(_Float16)(acc[i][1]+b1)))<<16);
    pw.y = ((uint32_t)__builtin_bit_cast(unsigned short,(_Float16)(acc[i][2]+b2))) |
           (((uint32_t)__builtin_bit_cast(unsigned short,(_Float16)(acc[i][3]+b3)))<<16);
    *(uint2*)&C[(size_t)mm*768 + g*256 + (c0>>1)] = pw;
  }
}

// ---------------- launch ----------------
extern "C" void kernel_launch(void* const* d_in, const int* in_sizes, int n_in,
                              void* d_out, int out_size, void* d_ws, size_t ws_size,
                              hipStream_t stream)
{
  const float* state = (const float*)d_in[0];   // (4096, 129)
  const float* hprev = (const float*)d_in[1];   // (2, 512)
  const int*   mask  = (const int*)d_in[2];     // (64, 64)
  const float* Wih0  = (const float*)d_in[3];   // (1536, 128)
  const float* Whh0  = (const float*)d_in[4];   // (1536, 512)
  const float* bih0  = (const float*)d_in[5];
  const float* bhh0  = (const float*)d_in[6];
  const float* Wih1  = (const float*)d_in[7];   // (1536, 512)
  const float* Whh1  = (const float*)d_in[8];   // (1536, 512)
  const float* bih1  = (const float*)d_in[9];
  const float* bhh1  = (const float*)d_in[10];
  const float* Wfc   = (const float*)d_in[11];  // (4096, 512)
  const float* bfc   = (const float*)d_in[12];

  if (ws_size < WS_NEED) return;

  float* out = (float*)d_out;
  char*  ws  = (char*)d_ws;
  uint32_t* gi0h = (uint32_t*)(ws + GI0H_OFF);
  float* H1  = (float*)(ws + H1_OFF);
  u64t*  mb0l0 = (u64t*)(ws + MB0L0_OFF);
  u64t*  mb0l1 = (u64t*)(ws + MB0L1_OFF);
  u64t*  mb1l1 = (u64t*)(ws + MB1L1_OFF);
  unsigned* progS = (unsigned*)(ws + PROGS_OFF);
  unsigned* progH = (unsigned*)(ws + PROGH_OFF);
  unsigned* tick  = (unsigned*)(ws + TICK_OFF);

  // clear mailboxes/progress/ticket each call (graph replays reuse ws; tag 0 never valid)
  (void)hipMemsetAsync(ws + MB0L0_OFF, 0, (size_t)(WS_NEED - MB0L0_OFF), stream);

  // gi0 precompute (f16-packed): M=4096, N=1536, K=128
  {
    dim3 grid(1536/64, 4096/64);
    gemm_gi0<<<grid, 256, 0, stream>>>(state+1, 129, Wih0, 128, gi0h, bih0, 128);
  }

  actor_fused<<<256, 512, 0, stream>>>(
      hprev, mask, Whh0, bhh0, Wih1, Whh1, bih1, bhh1, Wfc, bfc,
      gi0h, H1, mb0l0, mb0l1, mb1l1, progS, progH, tick,
      out, out + (size_t)4096*4096);
}